// Round 1
// baseline (776.963 us; speedup 1.0000x reference)
//
#include <hip/hip_runtime.h>
#include <math.h>

#define T_DIM 8192
#define B_DIM 4
#define INDIM 512
#define DV 512
#define DK 64
#define CHUNK 128
#define NCH (T_DIM / CHUNK)     // 64
#define ROWS (T_DIM * B_DIM)    // 32768
#define EPSF 1e-8f

// ---------------------------------------------------------------------------
// K1: fused projection GEMM.  out cols: [0,512)=v, [512,576)=k, [576,640)=q,
// [640,704)=a(sigmoid).  64x64 tile per block, BK=16, 4x4 micro-tile.
// ---------------------------------------------------------------------------
__global__ __launch_bounds__(256) void proj_kernel(
    const float* __restrict__ x,
    const float* __restrict__ Wv, const float* __restrict__ bv,
    const float* __restrict__ Wk, const float* __restrict__ bk,
    const float* __restrict__ Wq, const float* __restrict__ bq,
    const float* __restrict__ Wa, const float* __restrict__ ba,
    float* __restrict__ v_ws, float* __restrict__ k_ws,
    float* __restrict__ q_ws, float* __restrict__ a_ws)
{
  const int rowTile = blockIdx.x;   // 512 tiles of 64 rows
  const int colTile = blockIdx.y;   // 11 tiles of 64 cols
  const int tid = threadIdx.x;
  const int tx = tid & 15, ty = tid >> 4;

  const float* Wsel; const float* bsel; int colBase;
  if (colTile < 8)       { Wsel = Wv; bsel = bv; colBase = colTile * 64; }
  else if (colTile == 8) { Wsel = Wk; bsel = bk; colBase = 0; }
  else if (colTile == 9) { Wsel = Wq; bsel = bq; colBase = 0; }
  else                   { Wsel = Wa; bsel = ba; colBase = 0; }

  __shared__ float As[64][17];
  __shared__ float Bs[64][17];

  float acc[4][4] = {};
  const int r0  = rowTile * 64;
  const int m_l = tid >> 2;        // 0..63
  const int kq  = (tid & 3) * 4;   // 0,4,8,12

  for (int k0 = 0; k0 < INDIM; k0 += 16) {
    {
      const float4 xa = *(const float4*)&x[(size_t)(r0 + m_l) * INDIM + k0 + kq];
      As[m_l][kq + 0] = xa.x; As[m_l][kq + 1] = xa.y;
      As[m_l][kq + 2] = xa.z; As[m_l][kq + 3] = xa.w;
      const float4 wb = *(const float4*)&Wsel[(size_t)(colBase + m_l) * INDIM + k0 + kq];
      Bs[m_l][kq + 0] = wb.x; Bs[m_l][kq + 1] = wb.y;
      Bs[m_l][kq + 2] = wb.z; Bs[m_l][kq + 3] = wb.w;
    }
    __syncthreads();
#pragma unroll
    for (int k = 0; k < 16; ++k) {
      float a[4], b[4];
#pragma unroll
      for (int i = 0; i < 4; ++i) a[i] = As[ty * 4 + i][k];
#pragma unroll
      for (int j = 0; j < 4; ++j) b[j] = Bs[tx * 4 + j][k];
#pragma unroll
      for (int i = 0; i < 4; ++i)
#pragma unroll
        for (int j = 0; j < 4; ++j) acc[i][j] += a[i] * b[j];
    }
    __syncthreads();
  }

#pragma unroll
  for (int i = 0; i < 4; ++i) {
    const int r = r0 + ty * 4 + i;
#pragma unroll
    for (int j = 0; j < 4; ++j) {
      const int nl  = tx * 4 + j;
      float val = acc[i][j] + bsel[colBase + nl];
      if (colTile < 8) {
        v_ws[(size_t)r * DV + colBase + nl] = val;
      } else if (colTile == 8) {
        k_ws[(size_t)r * DK + nl] = val;
      } else if (colTile == 9) {
        q_ws[(size_t)r * DK + nl] = val;
      } else {
        a_ws[(size_t)r * DK + nl] = 1.0f / (1.0f + expf(-val));
      }
    }
  }
}

// ---------------------------------------------------------------------------
// K2: per-chunk cumprod; q_ws <- q*p (q_t), k_ws <- k/(p+eps) (k_t), pend.
// grid = nC, block = 256 = (b,n). idx = t_global*256 + tid (coalesced).
// ---------------------------------------------------------------------------
__global__ __launch_bounds__(256) void prep_kernel(
    const float* __restrict__ a_ws, float* __restrict__ q_ws,
    float* __restrict__ k_ws, float* __restrict__ pend)
{
  const int c = blockIdx.x;
  const int tid = threadIdx.x;
  float p = 1.0f;
  int idx = c * CHUNK * 256 + tid;
#pragma unroll 4
  for (int t = 0; t < CHUNK; ++t, idx += 256) {
    const float a = a_ws[idx];
    p *= fmaxf(a, EPSF);
    q_ws[idx] = q_ws[idx] * p;
    k_ws[idx] = k_ws[idx] / (p + EPSF);
  }
  pend[c * 256 + tid] = p;
}

// ---------------------------------------------------------------------------
// K3a: A = tril(q_t @ k_t^T) per (c,b).  128x128 out, K=64, 8x8 micro-tile.
// ---------------------------------------------------------------------------
__global__ __launch_bounds__(256) void score_kernel(
    const float* __restrict__ q_ws, const float* __restrict__ k_ws,
    float* __restrict__ A_ws)
{
  const int c = blockIdx.x, b = blockIdx.y;
  const int tid = threadIdx.x;
  __shared__ float qs[CHUNK][DK + 1];
  __shared__ float ks[CHUNK][DK + 1];
  const int base = c * CHUNK * 256 + b * 64;
  for (int f = tid; f < CHUNK * DK; f += 256) {
    const int t = f >> 6, n = f & 63;
    qs[t][n] = q_ws[base + t * 256 + n];
    ks[t][n] = k_ws[base + t * 256 + n];
  }
  __syncthreads();
  const int t0 = (tid >> 4) * 8;
  const int s0 = (tid & 15) * 8;
  float acc[8][8] = {};
#pragma unroll 4
  for (int n = 0; n < DK; ++n) {
    float a[8], bb[8];
#pragma unroll
    for (int i = 0; i < 8; ++i) a[i]  = qs[t0 + i][n];
#pragma unroll
    for (int j = 0; j < 8; ++j) bb[j] = ks[s0 + j][n];
#pragma unroll
    for (int i = 0; i < 8; ++i)
#pragma unroll
      for (int j = 0; j < 8; ++j) acc[i][j] += a[i] * bb[j];
  }
  float* Ab = A_ws + (size_t)(c * B_DIM + b) * CHUNK * CHUNK;
#pragma unroll
  for (int i = 0; i < 8; ++i) {
    const int t = t0 + i;
#pragma unroll
    for (int j = 0; j < 8; ++j) {
      const int s = s0 + j;
      Ab[t * CHUNK + s] = (s <= t) ? acc[i][j] : 0.0f;
    }
  }
}

// ---------------------------------------------------------------------------
// K3c: W_c[d,n] = (sum_t v[t,d] * k_t[t,n]) * pend[n], per (c,b,dtile of 128).
// ---------------------------------------------------------------------------
__global__ __launch_bounds__(256) void wchunk_kernel(
    const float* __restrict__ v_ws, const float* __restrict__ k_ws,
    const float* __restrict__ pend, float* __restrict__ W_ws)
{
  const int c = blockIdx.x, b = blockIdx.y, dt = blockIdx.z; // dt: 4 x 128 d
  __shared__ float Vs[32][129];
  __shared__ float Ks[32][65];
  const int tid = threadIdx.x;
  const int d0 = (tid >> 4) * 8;
  const int n0 = (tid & 15) * 4;
  float acc[8][4] = {};
  for (int kb = 0; kb < CHUNK; kb += 32) {
    for (int f = tid; f < 32 * 128; f += 256) {
      const int kk = f >> 7, d = f & 127;
      Vs[kk][d] = v_ws[(size_t)((c * CHUNK + kb + kk) * B_DIM + b) * DV + dt * 128 + d];
    }
    for (int f = tid; f < 32 * 64; f += 256) {
      const int kk = f >> 6, n = f & 63;
      Ks[kk][n] = k_ws[(c * CHUNK + kb + kk) * 256 + b * 64 + n];
    }
    __syncthreads();
#pragma unroll 4
    for (int kk = 0; kk < 32; ++kk) {
      float vr[8], kr[4];
#pragma unroll
      for (int i = 0; i < 8; ++i) vr[i] = Vs[kk][d0 + i];
#pragma unroll
      for (int j = 0; j < 4; ++j) kr[j] = Ks[kk][n0 + j];
#pragma unroll
      for (int i = 0; i < 8; ++i)
#pragma unroll
        for (int j = 0; j < 4; ++j) acc[i][j] += vr[i] * kr[j];
    }
    __syncthreads();
  }
  const float* pe = pend + c * 256 + b * 64;
  float pj[4];
#pragma unroll
  for (int j = 0; j < 4; ++j) pj[j] = pe[n0 + j];
  float* Wb = W_ws + ((size_t)(c * B_DIM + b) * DV + dt * 128) * DK;
#pragma unroll
  for (int i = 0; i < 8; ++i)
#pragma unroll
    for (int j = 0; j < 4; ++j)
      Wb[(d0 + i) * DK + n0 + j] = acc[i][j] * pj[j];
}

// ---------------------------------------------------------------------------
// K4: state scan over chunks, in place over W_ws: Sbuf[c] = S_c (pre-update).
// One thread per (b,d,n) element; 64 sequential steps.
// ---------------------------------------------------------------------------
__global__ __launch_bounds__(256) void scan_kernel(
    float* __restrict__ W_ws, const float* __restrict__ pend)
{
  const int flat = blockIdx.x * 256 + threadIdx.x;  // (b*512+d)*64 + n
  const int n = flat & 63;
  const int bd = flat >> 6;
  const int b = bd >> 9;
  float s = 0.0f;
  for (int c = 0; c < NCH; ++c) {
    const int off = c * 131072 + flat;
    const float w = W_ws[off];
    W_ws[off] = s;
    s = s * pend[c * 256 + b * 64 + n] + w;
  }
}

// ---------------------------------------------------------------------------
// K5: y = A @ v_ch + q_t @ S_c^T, per (c,b,dtile of 64). Writes d_out.
// ---------------------------------------------------------------------------
__global__ __launch_bounds__(256) void out_kernel(
    const float* __restrict__ A_ws, const float* __restrict__ v_ws,
    const float* __restrict__ q_ws, const float* __restrict__ W_ws,
    float* __restrict__ out)
{
  const int c = blockIdx.x, b = blockIdx.y, dt = blockIdx.z;  // dt: 8 x 64 d
  __shared__ float As[CHUNK][33];
  __shared__ float Vs[32][65];
  __shared__ float Qs[CHUNK][DK + 1];
  __shared__ float Ss[64][DK + 1];
  const int tid = threadIdx.x;
  const int t0 = (tid >> 4) * 8;
  const int d0 = (tid & 15) * 4;
  float acc[8][4] = {};
  const float* Ab = A_ws + (size_t)(c * B_DIM + b) * CHUNK * CHUNK;

  // intra-chunk: acc += A @ v_tile
  for (int kb = 0; kb < CHUNK; kb += 32) {
    for (int f = tid; f < CHUNK * 32; f += 256) {
      const int t = f >> 5, ss = f & 31;
      As[t][ss] = Ab[t * CHUNK + kb + ss];
    }
    for (int f = tid; f < 32 * 64; f += 256) {
      const int kk = f >> 6, d = f & 63;
      Vs[kk][d] = v_ws[(size_t)((c * CHUNK + kb + kk) * B_DIM + b) * DV + dt * 64 + d];
    }
    __syncthreads();
#pragma unroll 4
    for (int kk = 0; kk < 32; ++kk) {
      float a[8], vv[4];
#pragma unroll
      for (int i = 0; i < 8; ++i) a[i]  = As[t0 + i][kk];
#pragma unroll
      for (int j = 0; j < 4; ++j) vv[j] = Vs[kk][d0 + j];
#pragma unroll
      for (int i = 0; i < 8; ++i)
#pragma unroll
        for (int j = 0; j < 4; ++j) acc[i][j] += a[i] * vv[j];
    }
    __syncthreads();
  }

  // cross-chunk: acc += q_t @ S_c^T
  for (int f = tid; f < CHUNK * DK; f += 256) {
    const int t = f >> 6, n = f & 63;
    Qs[t][n] = q_ws[c * CHUNK * 256 + t * 256 + b * 64 + n];
  }
  for (int f = tid; f < 64 * 64; f += 256) {
    const int d = f >> 6, n = f & 63;
    Ss[d][n] = W_ws[((size_t)(c * B_DIM + b) * DV + dt * 64 + d) * DK + n];
  }
  __syncthreads();
#pragma unroll 4
  for (int n = 0; n < DK; ++n) {
    float a[8], sv[4];
#pragma unroll
    for (int i = 0; i < 8; ++i) a[i]  = Qs[t0 + i][n];
#pragma unroll
    for (int j = 0; j < 4; ++j) sv[j] = Ss[d0 + j][n];
#pragma unroll
    for (int i = 0; i < 8; ++i)
#pragma unroll
      for (int j = 0; j < 4; ++j) acc[i][j] += a[i] * sv[j];
  }

#pragma unroll
  for (int i = 0; i < 8; ++i)
#pragma unroll
    for (int j = 0; j < 4; ++j)
      out[(size_t)((c * CHUNK + t0 + i) * B_DIM + b) * DV + dt * 64 + d0 + j] = acc[i][j];
}

// ---------------------------------------------------------------------------
extern "C" void kernel_launch(void* const* d_in, const int* in_sizes, int n_in,
                              void* d_out, int out_size, void* d_ws, size_t ws_size,
                              hipStream_t stream)
{
  const float* x  = (const float*)d_in[0];
  const float* Wv = (const float*)d_in[1];
  const float* bv = (const float*)d_in[2];
  const float* Wk = (const float*)d_in[3];
  const float* bk = (const float*)d_in[4];
  const float* Wq = (const float*)d_in[5];
  const float* bq = (const float*)d_in[6];
  const float* Wa = (const float*)d_in[7];
  const float* ba = (const float*)d_in[8];
  float* out = (float*)d_out;

  float* ws   = (float*)d_ws;
  float* v_ws = ws;                                      // 16,777,216
  float* k_ws = v_ws + (size_t)ROWS * DV;                //  2,097,152
  float* q_ws = k_ws + (size_t)ROWS * DK;                //  2,097,152
  float* a_ws = q_ws + (size_t)ROWS * DK;                //  2,097,152
  float* pend = a_ws + (size_t)ROWS * DK;                //     16,384
  float* A_ws = pend + NCH * B_DIM * DK;                 //  4,194,304
  float* W_ws = A_ws + (size_t)NCH * B_DIM * CHUNK * CHUNK; // 8,388,608
  // total ~142.7 MB of d_ws

  proj_kernel<<<dim3(ROWS / 64, 11), 256, 0, stream>>>(
      x, Wv, bv, Wk, bk, Wq, bq, Wa, ba, v_ws, k_ws, q_ws, a_ws);
  prep_kernel<<<NCH, 256, 0, stream>>>(a_ws, q_ws, k_ws, pend);
  score_kernel<<<dim3(NCH, B_DIM), 256, 0, stream>>>(q_ws, k_ws, A_ws);
  wchunk_kernel<<<dim3(NCH, B_DIM, 4), 256, 0, stream>>>(v_ws, k_ws, pend, W_ws);
  scan_kernel<<<(B_DIM * DV * DK) / 256, 256, 0, stream>>>(W_ws, pend);
  out_kernel<<<dim3(NCH, B_DIM, 8), 256, 0, stream>>>(A_ws, v_ws, q_ws, W_ws, out);
}

// Round 2
// 445.898 us; speedup vs baseline: 1.7425x; 1.7425x over previous
//
#include <hip/hip_runtime.h>
#include <math.h>

#define T_DIM 8192
#define B_DIM 4
#define INDIM 512
#define DV 512
#define DK 64
#define CHUNK 128
#define NCH (T_DIM / CHUNK)     // 64
#define ROWS (T_DIM * B_DIM)    // 32768
#define NPAD 768                // 704 proj cols padded to 6x128
#define EPSF 1e-8f

typedef float float4_t __attribute__((ext_vector_type(4)));
typedef short short8_t __attribute__((ext_vector_type(8)));

__device__ inline unsigned short f2bf(float f) {
  unsigned int u = __float_as_uint(f);
  unsigned int r = (u + 0x7fffu + ((u >> 16) & 1u)) >> 16;
  return (unsigned short)r;
}
__device__ inline float bf2f(unsigned short h) {
  return __uint_as_float(((unsigned int)h) << 16);
}

__device__ inline void gload16(const void* g, void* l) {
  __builtin_amdgcn_global_load_lds(
      (const __attribute__((address_space(1))) void*)g,
      (__attribute__((address_space(3))) void*)l, 16, 0, 0);
}

// ---------------------------------------------------------------------------
// C0: split-cast x -> (x_hi, x_lo) bf16.  4 elems/thread.
// ---------------------------------------------------------------------------
__global__ __launch_bounds__(256) void cast_x_kernel(
    const float* __restrict__ x, unsigned short* __restrict__ xh,
    unsigned short* __restrict__ xl)
{
  const size_t i4 = ((size_t)blockIdx.x * 256 + threadIdx.x) * 4;
  const float4 v = *(const float4*)&x[i4];
  ushort4 h, l;
  h.x = f2bf(v.x); l.x = f2bf(v.x - bf2f(h.x));
  h.y = f2bf(v.y); l.y = f2bf(v.y - bf2f(h.y));
  h.z = f2bf(v.z); l.z = f2bf(v.z - bf2f(h.z));
  h.w = f2bf(v.w); l.w = f2bf(v.w - bf2f(h.w));
  *(ushort4*)&xh[i4] = h;
  *(ushort4*)&xl[i4] = l;
}

// ---------------------------------------------------------------------------
// C1: build padded concatenated weights (768x512) hi/lo + bias vector.
// rows: [0,512)=Wv [512,576)=Wk [576,640)=Wq [640,704)=Wa [704,768)=0
// ---------------------------------------------------------------------------
__global__ __launch_bounds__(256) void cast_w_kernel(
    const float* __restrict__ Wv, const float* __restrict__ Wk,
    const float* __restrict__ Wq, const float* __restrict__ Wa,
    const float* __restrict__ bv, const float* __restrict__ bk,
    const float* __restrict__ bq, const float* __restrict__ ba,
    unsigned short* __restrict__ wh, unsigned short* __restrict__ wl,
    float* __restrict__ bcat)
{
  const int t = blockIdx.x * 256 + threadIdx.x;      // 98304 threads
  const size_t i4 = (size_t)t * 4;
  const int row = (int)(i4 >> 9);                    // /512
  const int col = (int)(i4 & 511);
  float4 v = {0.f, 0.f, 0.f, 0.f};
  if (row < 512)      v = *(const float4*)&Wv[(size_t)row * INDIM + col];
  else if (row < 576) v = *(const float4*)&Wk[(size_t)(row - 512) * INDIM + col];
  else if (row < 640) v = *(const float4*)&Wq[(size_t)(row - 576) * INDIM + col];
  else if (row < 704) v = *(const float4*)&Wa[(size_t)(row - 640) * INDIM + col];
  ushort4 h, l;
  h.x = f2bf(v.x); l.x = f2bf(v.x - bf2f(h.x));
  h.y = f2bf(v.y); l.y = f2bf(v.y - bf2f(h.y));
  h.z = f2bf(v.z); l.z = f2bf(v.z - bf2f(h.z));
  h.w = f2bf(v.w); l.w = f2bf(v.w - bf2f(h.w));
  *(ushort4*)&wh[i4] = h;
  *(ushort4*)&wl[i4] = l;
  if (t < NPAD) {
    float b = 0.f;
    if (t < 512)      b = bv[t];
    else if (t < 576) b = bk[t - 512];
    else if (t < 640) b = bq[t - 576];
    else if (t < 704) b = ba[t - 640];
    bcat[t] = b;
  }
}

// ---------------------------------------------------------------------------
// K1: split-bf16 MFMA projection GEMM.  C = x @ Wcat^T  (M=32768,K=512,N=768)
// 128x128 tile, BK=32, 4 waves each 64x64 (4x4 of 16x16x32 MFMA),
// 3 MFMAs per tile (hi*hi + lo*hi + hi*lo).  Fused bias/sigmoid/scatter.
// ---------------------------------------------------------------------------
__global__ __launch_bounds__(256) void proj_mfma_kernel(
    const unsigned short* __restrict__ xh, const unsigned short* __restrict__ xl,
    const unsigned short* __restrict__ wh, const unsigned short* __restrict__ wl,
    const float* __restrict__ bcat,
    float* __restrict__ v_ws, float* __restrict__ k_ws,
    float* __restrict__ q_ws, float* __restrict__ a_ws)
{
  __shared__ __align__(16) unsigned short Ah[128 * 32];
  __shared__ __align__(16) unsigned short Al[128 * 32];
  __shared__ __align__(16) unsigned short Bh[128 * 32];
  __shared__ __align__(16) unsigned short Bl[128 * 32];

  const int tid  = threadIdx.x;
  const int r0   = blockIdx.x * 128;
  const int c0   = blockIdx.y * 128;
  const int wave = tid >> 6, lane = tid & 63;
  const int wm   = (wave & 1) * 64, wn = (wave >> 1) * 64;
  const int fm   = lane & 15;          // fragment row/col within 16
  const int fk   = (lane >> 4) * 8;    // k-offset within 32

  float4_t acc[4][4];
#pragma unroll
  for (int i = 0; i < 4; ++i)
#pragma unroll
    for (int j = 0; j < 4; ++j) acc[i][j] = (float4_t)0.0f;

  const int srow = tid >> 2;           // 0..63
  const int scol = (tid & 3) * 8;      // 0,8,16,24

  for (int k0 = 0; k0 < INDIM; k0 += 32) {
    // stage A(hi,lo) rows r0..r0+127, B(hi,lo) rows c0..c0+127, 32 k each
    const size_t ga0 = (size_t)(r0 + srow) * INDIM + k0 + scol;
    const size_t ga1 = (size_t)(r0 + 64 + srow) * INDIM + k0 + scol;
    const size_t gb0 = (size_t)(c0 + srow) * INDIM + k0 + scol;
    const size_t gb1 = (size_t)(c0 + 64 + srow) * INDIM + k0 + scol;
    gload16(&xh[ga0], &Ah[tid * 8]);
    gload16(&xh[ga1], &Ah[(256 + tid) * 8]);
    gload16(&xl[ga0], &Al[tid * 8]);
    gload16(&xl[ga1], &Al[(256 + tid) * 8]);
    gload16(&wh[gb0], &Bh[tid * 8]);
    gload16(&wh[gb1], &Bh[(256 + tid) * 8]);
    gload16(&wl[gb0], &Bl[tid * 8]);
    gload16(&wl[gb1], &Bl[(256 + tid) * 8]);
    __syncthreads();

    short8_t a_hi[4], a_lo[4], b_hi[4], b_lo[4];
#pragma unroll
    for (int i = 0; i < 4; ++i) {
      const int ar = (wm + i * 16 + fm) * 32 + fk;
      a_hi[i] = *(const short8_t*)&Ah[ar];
      a_lo[i] = *(const short8_t*)&Al[ar];
    }
#pragma unroll
    for (int j = 0; j < 4; ++j) {
      const int br = (wn + j * 16 + fm) * 32 + fk;
      b_hi[j] = *(const short8_t*)&Bh[br];
      b_lo[j] = *(const short8_t*)&Bl[br];
    }
#pragma unroll
    for (int i = 0; i < 4; ++i)
#pragma unroll
      for (int j = 0; j < 4; ++j) {
        acc[i][j] = __builtin_amdgcn_mfma_f32_16x16x32_bf16(a_hi[i], b_hi[j], acc[i][j], 0, 0, 0);
        acc[i][j] = __builtin_amdgcn_mfma_f32_16x16x32_bf16(a_lo[i], b_hi[j], acc[i][j], 0, 0, 0);
        acc[i][j] = __builtin_amdgcn_mfma_f32_16x16x32_bf16(a_hi[i], b_lo[j], acc[i][j], 0, 0, 0);
      }
    __syncthreads();
  }

  // epilogue: C/D layout col=lane&15, row=(lane>>4)*4+reg
#pragma unroll
  for (int j = 0; j < 4; ++j) {
    const int col = c0 + wn + j * 16 + fm;
    if (col >= 704) continue;
    const float bias = bcat[col];
#pragma unroll
    for (int i = 0; i < 4; ++i) {
#pragma unroll
      for (int r = 0; r < 4; ++r) {
        const int row = r0 + wm + i * 16 + (lane >> 4) * 4 + r;
        const float val = acc[i][j][r] + bias;
        if (col < 512)      v_ws[(size_t)row * DV + col] = val;
        else if (col < 576) k_ws[(size_t)row * DK + col - 512] = val;
        else if (col < 640) q_ws[(size_t)row * DK + col - 576] = val;
        else                a_ws[(size_t)row * DK + col - 640] = 1.0f / (1.0f + expf(-val));
      }
    }
  }
}

// ---------------------------------------------------------------------------
// K2: per-chunk cumprod; q_ws <- q*p (q_t), k_ws <- k/(p+eps) (k_t), pend.
// ---------------------------------------------------------------------------
__global__ __launch_bounds__(256) void prep_kernel(
    const float* __restrict__ a_ws, float* __restrict__ q_ws,
    float* __restrict__ k_ws, float* __restrict__ pend)
{
  const int c = blockIdx.x;
  const int tid = threadIdx.x;
  float p = 1.0f;
  int idx = c * CHUNK * 256 + tid;
#pragma unroll 4
  for (int t = 0; t < CHUNK; ++t, idx += 256) {
    const float a = a_ws[idx];
    p *= fmaxf(a, EPSF);
    q_ws[idx] = q_ws[idx] * p;
    k_ws[idx] = k_ws[idx] / (p + EPSF);
  }
  pend[c * 256 + tid] = p;
}

// ---------------------------------------------------------------------------
// K3a: A = tril(q_t @ k_t^T) per (c,b).
// ---------------------------------------------------------------------------
__global__ __launch_bounds__(256) void score_kernel(
    const float* __restrict__ q_ws, const float* __restrict__ k_ws,
    float* __restrict__ A_ws)
{
  const int c = blockIdx.x, b = blockIdx.y;
  const int tid = threadIdx.x;
  __shared__ float qs[CHUNK][DK + 1];
  __shared__ float ks[CHUNK][DK + 1];
  const int base = c * CHUNK * 256 + b * 64;
  for (int f = tid; f < CHUNK * DK; f += 256) {
    const int t = f >> 6, n = f & 63;
    qs[t][n] = q_ws[base + t * 256 + n];
    ks[t][n] = k_ws[base + t * 256 + n];
  }
  __syncthreads();
  const int t0 = (tid >> 4) * 8;
  const int s0 = (tid & 15) * 8;
  float acc[8][8] = {};
#pragma unroll 4
  for (int n = 0; n < DK; ++n) {
    float a[8], bb[8];
#pragma unroll
    for (int i = 0; i < 8; ++i) a[i]  = qs[t0 + i][n];
#pragma unroll
    for (int j = 0; j < 8; ++j) bb[j] = ks[s0 + j][n];
#pragma unroll
    for (int i = 0; i < 8; ++i)
#pragma unroll
      for (int j = 0; j < 8; ++j) acc[i][j] += a[i] * bb[j];
  }
  float* Ab = A_ws + (size_t)(c * B_DIM + b) * CHUNK * CHUNK;
#pragma unroll
  for (int i = 0; i < 8; ++i) {
    const int t = t0 + i;
#pragma unroll
    for (int j = 0; j < 8; ++j) {
      const int s = s0 + j;
      Ab[t * CHUNK + s] = (s <= t) ? acc[i][j] : 0.0f;
    }
  }
}

// ---------------------------------------------------------------------------
// K3c: W_c[d,n] = (sum_t v[t,d] * k_t[t,n]) * pend[n]
// ---------------------------------------------------------------------------
__global__ __launch_bounds__(256) void wchunk_kernel(
    const float* __restrict__ v_ws, const float* __restrict__ k_ws,
    const float* __restrict__ pend, float* __restrict__ W_ws)
{
  const int c = blockIdx.x, b = blockIdx.y, dt = blockIdx.z;
  __shared__ float Vs[32][129];
  __shared__ float Ks[32][65];
  const int tid = threadIdx.x;
  const int d0 = (tid >> 4) * 8;
  const int n0 = (tid & 15) * 4;
  float acc[8][4] = {};
  for (int kb = 0; kb < CHUNK; kb += 32) {
    for (int f = tid; f < 32 * 128; f += 256) {
      const int kk = f >> 7, d = f & 127;
      Vs[kk][d] = v_ws[(size_t)((c * CHUNK + kb + kk) * B_DIM + b) * DV + dt * 128 + d];
    }
    for (int f = tid; f < 32 * 64; f += 256) {
      const int kk = f >> 6, n = f & 63;
      Ks[kk][n] = k_ws[(c * CHUNK + kb + kk) * 256 + b * 64 + n];
    }
    __syncthreads();
#pragma unroll 4
    for (int kk = 0; kk < 32; ++kk) {
      float vr[8], kr[4];
#pragma unroll
      for (int i = 0; i < 8; ++i) vr[i] = Vs[kk][d0 + i];
#pragma unroll
      for (int j = 0; j < 4; ++j) kr[j] = Ks[kk][n0 + j];
#pragma unroll
      for (int i = 0; i < 8; ++i)
#pragma unroll
        for (int j = 0; j < 4; ++j) acc[i][j] += vr[i] * kr[j];
    }
    __syncthreads();
  }
  const float* pe = pend + c * 256 + b * 64;
  float pj[4];
#pragma unroll
  for (int j = 0; j < 4; ++j) pj[j] = pe[n0 + j];
  float* Wb = W_ws + ((size_t)(c * B_DIM + b) * DV + dt * 128) * DK;
#pragma unroll
  for (int i = 0; i < 8; ++i)
#pragma unroll
    for (int j = 0; j < 4; ++j)
      Wb[(d0 + i) * DK + n0 + j] = acc[i][j] * pj[j];
}

// ---------------------------------------------------------------------------
// K4: sequential state scan over chunks (in place; W_ws[c] <- S_c pre-update)
// ---------------------------------------------------------------------------
__global__ __launch_bounds__(256) void scan_kernel(
    float* __restrict__ W_ws, const float* __restrict__ pend)
{
  const int flat = blockIdx.x * 256 + threadIdx.x;
  const int n = flat & 63;
  const int bd = flat >> 6;
  const int b = bd >> 9;
  float s = 0.0f;
  for (int c = 0; c < NCH; ++c) {
    const int off = c * 131072 + flat;
    const float w = W_ws[off];
    W_ws[off] = s;
    s = s * pend[c * 256 + b * 64 + n] + w;
  }
}

// ---------------------------------------------------------------------------
// K5: y = A @ v_ch + q_t @ S_c^T
// ---------------------------------------------------------------------------
__global__ __launch_bounds__(256) void out_kernel(
    const float* __restrict__ A_ws, const float* __restrict__ v_ws,
    const float* __restrict__ q_ws, const float* __restrict__ W_ws,
    float* __restrict__ out)
{
  const int c = blockIdx.x, b = blockIdx.y, dt = blockIdx.z;
  __shared__ float As[CHUNK][33];
  __shared__ float Vs[32][65];
  __shared__ float Qs[CHUNK][DK + 1];
  __shared__ float Ss[64][DK + 1];
  const int tid = threadIdx.x;
  const int t0 = (tid >> 4) * 8;
  const int d0 = (tid & 15) * 4;
  float acc[8][4] = {};
  const float* Ab = A_ws + (size_t)(c * B_DIM + b) * CHUNK * CHUNK;

  for (int kb = 0; kb < CHUNK; kb += 32) {
    for (int f = tid; f < CHUNK * 32; f += 256) {
      const int t = f >> 5, ss = f & 31;
      As[t][ss] = Ab[t * CHUNK + kb + ss];
    }
    for (int f = tid; f < 32 * 64; f += 256) {
      const int kk = f >> 6, d = f & 63;
      Vs[kk][d] = v_ws[(size_t)((c * CHUNK + kb + kk) * B_DIM + b) * DV + dt * 64 + d];
    }
    __syncthreads();
#pragma unroll 4
    for (int kk = 0; kk < 32; ++kk) {
      float a[8], vv[4];
#pragma unroll
      for (int i = 0; i < 8; ++i) a[i]  = As[t0 + i][kk];
#pragma unroll
      for (int j = 0; j < 4; ++j) vv[j] = Vs[kk][d0 + j];
#pragma unroll
      for (int i = 0; i < 8; ++i)
#pragma unroll
        for (int j = 0; j < 4; ++j) acc[i][j] += a[i] * vv[j];
    }
    __syncthreads();
  }

  for (int f = tid; f < CHUNK * DK; f += 256) {
    const int t = f >> 6, n = f & 63;
    Qs[t][n] = q_ws[c * CHUNK * 256 + t * 256 + b * 64 + n];
  }
  for (int f = tid; f < 64 * 64; f += 256) {
    const int d = f >> 6, n = f & 63;
    Ss[d][n] = W_ws[((size_t)(c * B_DIM + b) * DV + dt * 64 + d) * DK + n];
  }
  __syncthreads();
#pragma unroll 4
  for (int n = 0; n < DK; ++n) {
    float a[8], sv[4];
#pragma unroll
    for (int i = 0; i < 8; ++i) a[i]  = Qs[t0 + i][n];
#pragma unroll
    for (int j = 0; j < 4; ++j) sv[j] = Ss[d0 + j][n];
#pragma unroll
    for (int i = 0; i < 8; ++i)
#pragma unroll
      for (int j = 0; j < 4; ++j) acc[i][j] += a[i] * sv[j];
  }

#pragma unroll
  for (int i = 0; i < 8; ++i)
#pragma unroll
    for (int j = 0; j < 4; ++j)
      out[(size_t)((c * CHUNK + t0 + i) * B_DIM + b) * DV + dt * 64 + d0 + j] = acc[i][j];
}

// ---------------------------------------------------------------------------
extern "C" void kernel_launch(void* const* d_in, const int* in_sizes, int n_in,
                              void* d_out, int out_size, void* d_ws, size_t ws_size,
                              hipStream_t stream)
{
  const float* x  = (const float*)d_in[0];
  const float* Wv = (const float*)d_in[1];
  const float* bv = (const float*)d_in[2];
  const float* Wk = (const float*)d_in[3];
  const float* bk = (const float*)d_in[4];
  const float* Wq = (const float*)d_in[5];
  const float* bq = (const float*)d_in[6];
  const float* Wa = (const float*)d_in[7];
  const float* ba = (const float*)d_in[8];
  float* out = (float*)d_out;

  float* ws   = (float*)d_ws;
  float* v_ws = ws;                                         // 16,777,216 f
  float* k_ws = v_ws + (size_t)ROWS * DV;                   //  2,097,152 f
  float* q_ws = k_ws + (size_t)ROWS * DK;                   //  2,097,152 f
  float* a_ws = q_ws + (size_t)ROWS * DK;                   //  2,097,152 f
  float* pend = a_ws + (size_t)ROWS * DK;                   //     16,384 f
  float* A_ws = pend + NCH * B_DIM * DK;                    //  4,194,304 f
  float* W_ws = A_ws + (size_t)NCH * B_DIM * CHUNK * CHUNK; //  8,388,608 f
  float* bcat = W_ws + (size_t)NCH * B_DIM * DV * DK;       //        768 f
  unsigned short* xh = (unsigned short*)(bcat + NPAD);      // 16,777,216 us
  unsigned short* xl = xh + (size_t)ROWS * INDIM;           // 16,777,216 us
  unsigned short* wh = xl + (size_t)ROWS * INDIM;           //    393,216 us
  unsigned short* wl = wh + (size_t)NPAD * INDIM;           //    393,216 us
  // total ~211 MB of d_ws

  cast_x_kernel<<<(ROWS * INDIM / 4) / 256, 256, 0, stream>>>(x, xh, xl);
  cast_w_kernel<<<(NPAD * INDIM / 4) / 256, 256, 0, stream>>>(
      Wv, Wk, Wq, Wa, bv, bk, bq, ba, wh, wl, bcat);
  proj_mfma_kernel<<<dim3(ROWS / 128, NPAD / 128), 256, 0, stream>>>(
      xh, xl, wh, wl, bcat, v_ws, k_ws, q_ws, a_ws);
  prep_kernel<<<NCH, 256, 0, stream>>>(a_ws, q_ws, k_ws, pend);
  score_kernel<<<dim3(NCH, B_DIM), 256, 0, stream>>>(q_ws, k_ws, A_ws);
  wchunk_kernel<<<dim3(NCH, B_DIM, 4), 256, 0, stream>>>(v_ws, k_ws, pend, W_ws);
  scan_kernel<<<(B_DIM * DV * DK) / 256, 256, 0, stream>>>(W_ws, pend);
  out_kernel<<<dim3(NCH, B_DIM, 8), 256, 0, stream>>>(A_ws, v_ws, q_ws, W_ws, out);
}

// Round 3
// 387.575 us; speedup vs baseline: 2.0047x; 1.1505x over previous
//
#include <hip/hip_runtime.h>
#include <math.h>

#define T_DIM 8192
#define B_DIM 4
#define INDIM 512
#define DV 512
#define DK 64
#define CHUNK 128
#define NCH (T_DIM / CHUNK)     // 64
#define ROWS (T_DIM * B_DIM)    // 32768
#define NPAD 768                // 704 proj cols padded to 6x128
#define KCAT 192                // 128 intra + 64 state
#define EPSF 1e-8f

typedef float float4_t __attribute__((ext_vector_type(4)));
typedef short short8_t __attribute__((ext_vector_type(8)));

__device__ inline unsigned short f2bf(float f) {
  unsigned int u = __float_as_uint(f);
  unsigned int r = (u + 0x7fffu + ((u >> 16) & 1u)) >> 16;
  return (unsigned short)r;
}
__device__ inline float bf2f(unsigned short h) {
  return __uint_as_float(((unsigned int)h) << 16);
}

__device__ inline void gload16(const void* g, void* l) {
  __builtin_amdgcn_global_load_lds(
      (const __attribute__((address_space(1))) void*)g,
      (__attribute__((address_space(3))) void*)l, 16, 0, 0);
}

// ---------------------------------------------------------------------------
// C0: split-cast x -> (x_hi, x_lo) bf16.
// ---------------------------------------------------------------------------
__global__ __launch_bounds__(256) void cast_x_kernel(
    const float* __restrict__ x, unsigned short* __restrict__ xh,
    unsigned short* __restrict__ xl)
{
  const size_t i4 = ((size_t)blockIdx.x * 256 + threadIdx.x) * 4;
  const float4 v = *(const float4*)&x[i4];
  ushort4 h, l;
  h.x = f2bf(v.x); l.x = f2bf(v.x - bf2f(h.x));
  h.y = f2bf(v.y); l.y = f2bf(v.y - bf2f(h.y));
  h.z = f2bf(v.z); l.z = f2bf(v.z - bf2f(h.z));
  h.w = f2bf(v.w); l.w = f2bf(v.w - bf2f(h.w));
  *(ushort4*)&xh[i4] = h;
  *(ushort4*)&xl[i4] = l;
}

// ---------------------------------------------------------------------------
// C1: padded concatenated weights (768x512) hi/lo + bias vector.
// ---------------------------------------------------------------------------
__global__ __launch_bounds__(256) void cast_w_kernel(
    const float* __restrict__ Wv, const float* __restrict__ Wk,
    const float* __restrict__ Wq, const float* __restrict__ Wa,
    const float* __restrict__ bv, const float* __restrict__ bk,
    const float* __restrict__ bq, const float* __restrict__ ba,
    unsigned short* __restrict__ wh, unsigned short* __restrict__ wl,
    float* __restrict__ bcat)
{
  const int t = blockIdx.x * 256 + threadIdx.x;
  const size_t i4 = (size_t)t * 4;
  const int row = (int)(i4 >> 9);
  const int col = (int)(i4 & 511);
  float4 v = {0.f, 0.f, 0.f, 0.f};
  if (row < 512)      v = *(const float4*)&Wv[(size_t)row * INDIM + col];
  else if (row < 576) v = *(const float4*)&Wk[(size_t)(row - 512) * INDIM + col];
  else if (row < 640) v = *(const float4*)&Wq[(size_t)(row - 576) * INDIM + col];
  else if (row < 704) v = *(const float4*)&Wa[(size_t)(row - 640) * INDIM + col];
  ushort4 h, l;
  h.x = f2bf(v.x); l.x = f2bf(v.x - bf2f(h.x));
  h.y = f2bf(v.y); l.y = f2bf(v.y - bf2f(h.y));
  h.z = f2bf(v.z); l.z = f2bf(v.z - bf2f(h.z));
  h.w = f2bf(v.w); l.w = f2bf(v.w - bf2f(h.w));
  *(ushort4*)&wh[i4] = h;
  *(ushort4*)&wl[i4] = l;
  if (t < NPAD) {
    float b = 0.f;
    if (t < 512)      b = bv[t];
    else if (t < 576) b = bk[t - 512];
    else if (t < 640) b = bq[t - 576];
    else if (t < 704) b = ba[t - 640];
    bcat[t] = b;
  }
}

// ---------------------------------------------------------------------------
// K1: split-bf16 MFMA projection GEMM (M=32768,K=512,N=768), fused epilogue.
// v -> v_ws fp32, k -> k_ws fp32, q -> Acat cols [128,192) as bf16 hi/lo,
// alpha -> a_ws fp32 (sigmoid applied).
// ---------------------------------------------------------------------------
__global__ __launch_bounds__(256) void proj_mfma_kernel(
    const unsigned short* __restrict__ xh, const unsigned short* __restrict__ xl,
    const unsigned short* __restrict__ wh, const unsigned short* __restrict__ wl,
    const float* __restrict__ bcat,
    float* __restrict__ v_ws, float* __restrict__ k_ws,
    unsigned short* __restrict__ Acat_h, unsigned short* __restrict__ Acat_l,
    float* __restrict__ a_ws)
{
  __shared__ __align__(16) unsigned short Ah[128 * 32];
  __shared__ __align__(16) unsigned short Al[128 * 32];
  __shared__ __align__(16) unsigned short Bh[128 * 32];
  __shared__ __align__(16) unsigned short Bl[128 * 32];

  const int tid  = threadIdx.x;
  const int r0   = blockIdx.x * 128;
  const int c0   = blockIdx.y * 128;
  const int wave = tid >> 6, lane = tid & 63;
  const int wm   = (wave & 1) * 64, wn = (wave >> 1) * 64;
  const int fm   = lane & 15;
  const int fk   = (lane >> 4) * 8;

  float4_t acc[4][4];
#pragma unroll
  for (int i = 0; i < 4; ++i)
#pragma unroll
    for (int j = 0; j < 4; ++j) acc[i][j] = (float4_t)0.0f;

  const int srow = tid >> 2;
  const int scol = (tid & 3) * 8;

  for (int k0 = 0; k0 < INDIM; k0 += 32) {
    const size_t ga0 = (size_t)(r0 + srow) * INDIM + k0 + scol;
    const size_t ga1 = (size_t)(r0 + 64 + srow) * INDIM + k0 + scol;
    const size_t gb0 = (size_t)(c0 + srow) * INDIM + k0 + scol;
    const size_t gb1 = (size_t)(c0 + 64 + srow) * INDIM + k0 + scol;
    gload16(&xh[ga0], &Ah[tid * 8]);
    gload16(&xh[ga1], &Ah[(256 + tid) * 8]);
    gload16(&xl[ga0], &Al[tid * 8]);
    gload16(&xl[ga1], &Al[(256 + tid) * 8]);
    gload16(&wh[gb0], &Bh[tid * 8]);
    gload16(&wh[gb1], &Bh[(256 + tid) * 8]);
    gload16(&wl[gb0], &Bl[tid * 8]);
    gload16(&wl[gb1], &Bl[(256 + tid) * 8]);
    __syncthreads();

    short8_t a_hi[4], a_lo[4], b_hi[4], b_lo[4];
#pragma unroll
    for (int i = 0; i < 4; ++i) {
      const int ar = (wm + i * 16 + fm) * 32 + fk;
      a_hi[i] = *(const short8_t*)&Ah[ar];
      a_lo[i] = *(const short8_t*)&Al[ar];
    }
#pragma unroll
    for (int j = 0; j < 4; ++j) {
      const int br = (wn + j * 16 + fm) * 32 + fk;
      b_hi[j] = *(const short8_t*)&Bh[br];
      b_lo[j] = *(const short8_t*)&Bl[br];
    }
#pragma unroll
    for (int i = 0; i < 4; ++i)
#pragma unroll
      for (int j = 0; j < 4; ++j) {
        acc[i][j] = __builtin_amdgcn_mfma_f32_16x16x32_bf16(a_hi[i], b_hi[j], acc[i][j], 0, 0, 0);
        acc[i][j] = __builtin_amdgcn_mfma_f32_16x16x32_bf16(a_lo[i], b_hi[j], acc[i][j], 0, 0, 0);
        acc[i][j] = __builtin_amdgcn_mfma_f32_16x16x32_bf16(a_hi[i], b_lo[j], acc[i][j], 0, 0, 0);
      }
    __syncthreads();
  }

#pragma unroll
  for (int j = 0; j < 4; ++j) {
    const int col = c0 + wn + j * 16 + fm;
    if (col >= 704) continue;
    const float bias = bcat[col];
#pragma unroll
    for (int i = 0; i < 4; ++i) {
#pragma unroll
      for (int r = 0; r < 4; ++r) {
        const int row = r0 + wm + i * 16 + (lane >> 4) * 4 + r;  // row = t*4+b
        const float val = acc[i][j][r] + bias;
        if (col < 512) {
          v_ws[(size_t)row * DV + col] = val;
        } else if (col < 576) {
          k_ws[(size_t)row * DK + col - 512] = val;
        } else if (col < 640) {
          // raw q as bf16 hi/lo into Acat[:, 128+(col-576)]
          const int tg = row >> 2, bb = row & 3;
          const int cc = tg >> 7, tl = tg & 127;
          const size_t qa = ((size_t)(cc * 4 + bb) * 128 + tl) * KCAT + 128 + (col - 576);
          const unsigned short h = f2bf(val);
          Acat_h[qa] = h;
          Acat_l[qa] = f2bf(val - bf2f(h));
        } else {
          a_ws[(size_t)row * DK + col - 640] = 1.0f / (1.0f + expf(-val));
        }
      }
    }
  }
}

// ---------------------------------------------------------------------------
// K2: per-chunk cumprod.  k_ws <- k/(p+eps) in place; Acat q-cols <- q_t
// (read raw q hi/lo, scale by p, write back hi/lo); pend <- p_end.
// ---------------------------------------------------------------------------
__global__ __launch_bounds__(256) void prep_kernel(
    const float* __restrict__ a_ws, float* __restrict__ k_ws,
    unsigned short* __restrict__ Acat_h, unsigned short* __restrict__ Acat_l,
    float* __restrict__ pend)
{
  const int c = blockIdx.x;
  const int tid = threadIdx.x;          // b*64+n
  const int b = tid >> 6, n = tid & 63;
  float p = 1.0f;
  int idx = c * CHUNK * 256 + tid;
  size_t qa = ((size_t)(c * 4 + b) * 128) * KCAT + 128 + n;
#pragma unroll 4
  for (int t = 0; t < CHUNK; ++t, idx += 256, qa += KCAT) {
    const float a = a_ws[idx];
    p *= fmaxf(a, EPSF);
    const float q = bf2f(Acat_h[qa]) + bf2f(Acat_l[qa]);
    const float qt = q * p;
    const unsigned short h = f2bf(qt);
    Acat_h[qa] = h;
    Acat_l[qa] = f2bf(qt - bf2f(h));
    k_ws[idx] = k_ws[idx] / (p + EPSF);
  }
  pend[c * 256 + tid] = p;
}

// ---------------------------------------------------------------------------
// K3a: A = tril(q_t @ k_t^T) per (c,b), written as bf16 hi/lo into
// Acat cols [0,128).
// ---------------------------------------------------------------------------
__global__ __launch_bounds__(256) void score_kernel(
    const float* __restrict__ k_ws,
    unsigned short* __restrict__ Acat_h, unsigned short* __restrict__ Acat_l)
{
  const int c = blockIdx.x, b = blockIdx.y;
  const int cb = c * B_DIM + b;
  const int tid = threadIdx.x;
  __shared__ float qs[CHUNK][DK + 1];
  __shared__ float ks[CHUNK][DK + 1];
  const unsigned short* Aq_h = Acat_h + (size_t)cb * CHUNK * KCAT + 128;
  const unsigned short* Aq_l = Acat_l + (size_t)cb * CHUNK * KCAT + 128;
  const int kbase = c * CHUNK * 256 + b * 64;
  for (int f = tid; f < CHUNK * DK; f += 256) {
    const int t = f >> 6, n = f & 63;
    qs[t][n] = bf2f(Aq_h[t * KCAT + n]) + bf2f(Aq_l[t * KCAT + n]);
    ks[t][n] = k_ws[kbase + t * 256 + n];
  }
  __syncthreads();
  const int t0 = (tid >> 4) * 8;
  const int s0 = (tid & 15) * 8;
  float acc[8][8] = {};
#pragma unroll 4
  for (int n = 0; n < DK; ++n) {
    float a[8], bb[8];
#pragma unroll
    for (int i = 0; i < 8; ++i) a[i]  = qs[t0 + i][n];
#pragma unroll
    for (int j = 0; j < 8; ++j) bb[j] = ks[s0 + j][n];
#pragma unroll
    for (int i = 0; i < 8; ++i)
#pragma unroll
      for (int j = 0; j < 8; ++j) acc[i][j] += a[i] * bb[j];
  }
#pragma unroll
  for (int i = 0; i < 8; ++i) {
    const int t = t0 + i;
    unsigned short hv[8], lv[8];
#pragma unroll
    for (int j = 0; j < 8; ++j) {
      const float vv = ((s0 + j) <= t) ? acc[i][j] : 0.0f;
      hv[j] = f2bf(vv);
      lv[j] = f2bf(vv - bf2f(hv[j]));
    }
    const size_t oa = (size_t)cb * CHUNK * KCAT + (size_t)t * KCAT + s0;
#pragma unroll
    for (int j = 0; j < 8; ++j) { Acat_h[oa + j] = hv[j]; Acat_l[oa + j] = lv[j]; }
  }
}

// ---------------------------------------------------------------------------
// K3c: W_c[d,n] = (sum_t v[t,d] * k_t[t,n]) * pend[n]  (fp32 VALU, unchanged)
// ---------------------------------------------------------------------------
__global__ __launch_bounds__(256) void wchunk_kernel(
    const float* __restrict__ v_ws, const float* __restrict__ k_ws,
    const float* __restrict__ pend, float* __restrict__ W_ws)
{
  const int c = blockIdx.x, b = blockIdx.y, dt = blockIdx.z;
  __shared__ float Vs[32][129];
  __shared__ float Ks[32][65];
  const int tid = threadIdx.x;
  const int d0 = (tid >> 4) * 8;
  const int n0 = (tid & 15) * 4;
  float acc[8][4] = {};
  for (int kb = 0; kb < CHUNK; kb += 32) {
    for (int f = tid; f < 32 * 128; f += 256) {
      const int kk = f >> 7, d = f & 127;
      Vs[kk][d] = v_ws[(size_t)((c * CHUNK + kb + kk) * B_DIM + b) * DV + dt * 128 + d];
    }
    for (int f = tid; f < 32 * 64; f += 256) {
      const int kk = f >> 6, n = f & 63;
      Ks[kk][n] = k_ws[(c * CHUNK + kb + kk) * 256 + b * 64 + n];
    }
    __syncthreads();
#pragma unroll 4
    for (int kk = 0; kk < 32; ++kk) {
      float vr[8], kr[4];
#pragma unroll
      for (int i = 0; i < 8; ++i) vr[i] = Vs[kk][d0 + i];
#pragma unroll
      for (int j = 0; j < 4; ++j) kr[j] = Ks[kk][n0 + j];
#pragma unroll
      for (int i = 0; i < 8; ++i)
#pragma unroll
        for (int j = 0; j < 4; ++j) acc[i][j] += vr[i] * kr[j];
    }
    __syncthreads();
  }
  const float* pe = pend + c * 256 + b * 64;
  float pj[4];
#pragma unroll
  for (int j = 0; j < 4; ++j) pj[j] = pe[n0 + j];
  float* Wb = W_ws + ((size_t)(c * B_DIM + b) * DV + dt * 128) * DK;
#pragma unroll
  for (int i = 0; i < 8; ++i)
#pragma unroll
    for (int j = 0; j < 4; ++j)
      Wb[(d0 + i) * DK + n0 + j] = acc[i][j] * pj[j];
}

// ---------------------------------------------------------------------------
// K4: sequential state scan over chunks (in place; W_ws[c] <- S_c pre-update)
// ---------------------------------------------------------------------------
__global__ __launch_bounds__(256) void scan_kernel(
    float* __restrict__ W_ws, const float* __restrict__ pend)
{
  const int flat = blockIdx.x * 256 + threadIdx.x;
  const int n = flat & 63;
  const int bd = flat >> 6;
  const int b = bd >> 9;
  float s = 0.0f;
  for (int c = 0; c < NCH; ++c) {
    const int off = c * 131072 + flat;
    const float w = W_ws[off];
    W_ws[off] = s;
    s = s * pend[c * 256 + b * 64 + n] + w;
  }
}

// ---------------------------------------------------------------------------
// K4b: transpose-cast v -> Bt hi/lo, layout [(c,b)][d 0..511][s 0..127] bf16.
// grid (NCH, B_DIM, 8): 64-d slab each; LDS tile transpose.
// ---------------------------------------------------------------------------
__global__ __launch_bounds__(256) void vt_kernel(
    const float* __restrict__ v_ws,
    unsigned short* __restrict__ Bt_h, unsigned short* __restrict__ Bt_l)
{
  __shared__ float Ts[CHUNK][65];
  const int c = blockIdx.x, b = blockIdx.y, dblk = blockIdx.z;
  const int cb = c * B_DIM + b;
  const int d0 = dblk * 64;
  const int tid = threadIdx.x;
#pragma unroll
  for (int q = 0; q < 8; ++q) {
    const int idx = (q * 256 + tid) * 4;       // 0..8191
    const int s = idx >> 6, dd = idx & 63;
    const float4 v = *(const float4*)&v_ws[(size_t)((c * CHUNK + s) * B_DIM + b) * DV + d0 + dd];
    Ts[s][dd + 0] = v.x; Ts[s][dd + 1] = v.y;
    Ts[s][dd + 2] = v.z; Ts[s][dd + 3] = v.w;
  }
  __syncthreads();
#pragma unroll
  for (int q = 0; q < 8; ++q) {
    const int idx = (q * 256 + tid) * 4;
    const int dd = idx >> 7, s0 = idx & 127;
    float v0 = Ts[s0 + 0][dd], v1 = Ts[s0 + 1][dd];
    float v2 = Ts[s0 + 2][dd], v3 = Ts[s0 + 3][dd];
    ushort4 h, l;
    h.x = f2bf(v0); l.x = f2bf(v0 - bf2f(h.x));
    h.y = f2bf(v1); l.y = f2bf(v1 - bf2f(h.y));
    h.z = f2bf(v2); l.z = f2bf(v2 - bf2f(h.z));
    h.w = f2bf(v3); l.w = f2bf(v3 - bf2f(h.w));
    const size_t oa = ((size_t)cb * DV + d0 + dd) * CHUNK + s0;
    *(ushort4*)&Bt_h[oa] = h;
    *(ushort4*)&Bt_l[oa] = l;
  }
}

// ---------------------------------------------------------------------------
// K5: y = [A|q_t] @ [v ; S^T]  via split-bf16 MFMA.  M=128(t) N=128(d-tile)
// K=192.  Steps 0..3 stage B from Bt (v^T bf16); steps 4,5 convert S fp32.
// ---------------------------------------------------------------------------
__global__ __launch_bounds__(256) void out_mfma_kernel(
    const unsigned short* __restrict__ Acat_h, const unsigned short* __restrict__ Acat_l,
    const unsigned short* __restrict__ Bt_h, const unsigned short* __restrict__ Bt_l,
    const float* __restrict__ W_ws, float* __restrict__ out)
{
  __shared__ __align__(16) unsigned short Ah[128 * 32];
  __shared__ __align__(16) unsigned short Al[128 * 32];
  __shared__ __align__(16) unsigned short Bh[128 * 32];
  __shared__ __align__(16) unsigned short Bl[128 * 32];

  const int c = blockIdx.x, b = blockIdx.y, nt = blockIdx.z;
  const int cb = c * B_DIM + b;
  const int tid  = threadIdx.x;
  const int wave = tid >> 6, lane = tid & 63;
  const int wm   = (wave & 1) * 64, wn = (wave >> 1) * 64;
  const int fm   = lane & 15;
  const int fk   = (lane >> 4) * 8;

  const unsigned short* Ab_h = Acat_h + (size_t)cb * CHUNK * KCAT;
  const unsigned short* Ab_l = Acat_l + (size_t)cb * CHUNK * KCAT;
  const unsigned short* Bb_h = Bt_h + ((size_t)cb * DV + nt * 128) * CHUNK;
  const unsigned short* Bb_l = Bt_l + ((size_t)cb * DV + nt * 128) * CHUNK;
  const float* Sb = W_ws + ((size_t)cb * DV + nt * 128) * DK;

  float4_t acc[4][4];
#pragma unroll
  for (int i = 0; i < 4; ++i)
#pragma unroll
    for (int j = 0; j < 4; ++j) acc[i][j] = (float4_t)0.0f;

  for (int ks = 0; ks < 6; ++ks) {
    const int k0 = ks * 32;
    // A staging: 128 rows x 32 cols of Acat (row stride KCAT)
#pragma unroll
    for (int q = 0; q < 2; ++q) {
      const int flat = q * 2048 + tid * 8;
      const int row = flat >> 5, col = flat & 31;
      gload16(&Ab_h[(size_t)row * KCAT + k0 + col], &Ah[flat]);
      gload16(&Ab_l[(size_t)row * KCAT + k0 + col], &Al[flat]);
    }
    if (ks < 4) {
      // B staging from Bt (row stride CHUNK)
#pragma unroll
      for (int q = 0; q < 2; ++q) {
        const int flat = q * 2048 + tid * 8;
        const int row = flat >> 5, col = flat & 31;
        gload16(&Bb_h[(size_t)row * CHUNK + k0 + col], &Bh[flat]);
        gload16(&Bb_l[(size_t)row * CHUNK + k0 + col], &Bl[flat]);
      }
    } else {
      // B staging from S fp32 with in-register split-cast
#pragma unroll
      for (int q = 0; q < 4; ++q) {
        const int flat = (q * 256 + tid) * 4;   // 0..4095
        const int r = flat >> 5, n0 = flat & 31;
        const float4 sv = *(const float4*)&Sb[(size_t)r * DK + (k0 - 128) + n0];
        ushort4 h, l;
        h.x = f2bf(sv.x); l.x = f2bf(sv.x - bf2f(h.x));
        h.y = f2bf(sv.y); l.y = f2bf(sv.y - bf2f(h.y));
        h.z = f2bf(sv.z); l.z = f2bf(sv.z - bf2f(h.z));
        h.w = f2bf(sv.w); l.w = f2bf(sv.w - bf2f(h.w));
        *(ushort4*)&Bh[r * 32 + n0] = h;
        *(ushort4*)&Bl[r * 32 + n0] = l;
      }
    }
    __syncthreads();

    short8_t a_hi[4], a_lo[4], b_hi[4], b_lo[4];
#pragma unroll
    for (int i = 0; i < 4; ++i) {
      const int ar = (wm + i * 16 + fm) * 32 + fk;
      a_hi[i] = *(const short8_t*)&Ah[ar];
      a_lo[i] = *(const short8_t*)&Al[ar];
    }
#pragma unroll
    for (int j = 0; j < 4; ++j) {
      const int br = (wn + j * 16 + fm) * 32 + fk;
      b_hi[j] = *(const short8_t*)&Bh[br];
      b_lo[j] = *(const short8_t*)&Bl[br];
    }
#pragma unroll
    for (int i = 0; i < 4; ++i)
#pragma unroll
      for (int j = 0; j < 4; ++j) {
        acc[i][j] = __builtin_amdgcn_mfma_f32_16x16x32_bf16(a_hi[i], b_hi[j], acc[i][j], 0, 0, 0);
        acc[i][j] = __builtin_amdgcn_mfma_f32_16x16x32_bf16(a_lo[i], b_hi[j], acc[i][j], 0, 0, 0);
        acc[i][j] = __builtin_amdgcn_mfma_f32_16x16x32_bf16(a_hi[i], b_lo[j], acc[i][j], 0, 0, 0);
      }
    __syncthreads();
  }

#pragma unroll
  for (int j = 0; j < 4; ++j) {
    const int d = nt * 128 + wn + j * 16 + fm;
#pragma unroll
    for (int i = 0; i < 4; ++i) {
#pragma unroll
      for (int r = 0; r < 4; ++r) {
        const int t = c * CHUNK + wm + i * 16 + (lane >> 4) * 4 + r;
        out[((size_t)t * B_DIM + b) * DV + d] = acc[i][j][r];
      }
    }
  }
}

// ---------------------------------------------------------------------------
extern "C" void kernel_launch(void* const* d_in, const int* in_sizes, int n_in,
                              void* d_out, int out_size, void* d_ws, size_t ws_size,
                              hipStream_t stream)
{
  const float* x  = (const float*)d_in[0];
  const float* Wv = (const float*)d_in[1];
  const float* bv = (const float*)d_in[2];
  const float* Wk = (const float*)d_in[3];
  const float* bk = (const float*)d_in[4];
  const float* Wq = (const float*)d_in[5];
  const float* bq = (const float*)d_in[6];
  const float* Wa = (const float*)d_in[7];
  const float* ba = (const float*)d_in[8];
  float* out = (float*)d_out;

  // ---- workspace layout (total 211,356,672 B — same as proven round-2) ----
  float* ws   = (float*)d_ws;
  float* v_ws = ws;                                         // 16,777,216 f
  float* k_ws = v_ws + (size_t)ROWS * DV;                   //  2,097,152 f
  float* a_ws = k_ws + (size_t)ROWS * DK;                   //  2,097,152 f
  float* pend = a_ws + (size_t)ROWS * DK;                   //     16,384 f
  float* W_ws = pend + NCH * B_DIM * DK;                    //  8,388,608 f
  float* bcat = W_ws + (size_t)NCH * B_DIM * DV * DK;       //        768 f
  unsigned short* Acat_h = (unsigned short*)(bcat + NPAD);            // 6,291,456 us
  unsigned short* Acat_l = Acat_h + (size_t)NCH * B_DIM * CHUNK * KCAT;
  unsigned short* uni = Acat_l + (size_t)NCH * B_DIM * CHUNK * KCAT;
  // union A: proj staging (dead after proj_mfma)
  unsigned short* xh = uni;                                 // 16,777,216 us
  unsigned short* xl = xh + (size_t)ROWS * INDIM;           // 16,777,216 us
  unsigned short* wh = xl + (size_t)ROWS * INDIM;           //    393,216 us
  unsigned short* wl = wh + (size_t)NPAD * INDIM;           //    393,216 us
  // union B: v^T bf16 (written by vt_kernel after proj is done with x/w)
  unsigned short* Bt_h = uni;                               // 16,777,216 us
  unsigned short* Bt_l = Bt_h + (size_t)NCH * B_DIM * DV * CHUNK;

  cast_x_kernel<<<(ROWS * INDIM / 4) / 256, 256, 0, stream>>>(x, xh, xl);
  cast_w_kernel<<<(NPAD * INDIM / 4) / 256, 256, 0, stream>>>(
      Wv, Wk, Wq, Wa, bv, bk, bq, ba, wh, wl, bcat);
  proj_mfma_kernel<<<dim3(ROWS / 128, NPAD / 128), 256, 0, stream>>>(
      xh, xl, wh, wl, bcat, v_ws, k_ws, Acat_h, Acat_l, a_ws);
  prep_kernel<<<NCH, 256, 0, stream>>>(a_ws, k_ws, Acat_h, Acat_l, pend);
  score_kernel<<<dim3(NCH, B_DIM), 256, 0, stream>>>(k_ws, Acat_h, Acat_l);
  wchunk_kernel<<<dim3(NCH, B_DIM, 4), 256, 0, stream>>>(v_ws, k_ws, pend, W_ws);
  scan_kernel<<<(B_DIM * DV * DK) / 256, 256, 0, stream>>>(W_ws, pend);
  vt_kernel<<<dim3(NCH, B_DIM, 8), 256, 0, stream>>>(v_ws, Bt_h, Bt_l);   // after proj: Bt aliases xh/xl
  out_mfma_kernel<<<dim3(NCH, B_DIM, 4), 256, 0, stream>>>(
      Acat_h, Acat_l, Bt_h, Bt_l, W_ws, out);
}